// Round 6
// baseline (353.073 us; speedup 1.0000x reference)
//
#include <hip/hip_runtime.h>
#include <hip/hip_bf16.h>
#include <math.h>

constexpr int B_ = 8;
constexpr int C_ = 256;
constexpr int N_ = 2048;
constexpr int CN_ = C_ * N_;        // 524288
constexpr int TOT_ = B_ * C_ * N_;  // 4194304
constexpr int NTILES = 16;          // 128-wide strips
constexpr int NPAIRS = 136;         // triangular tiles per batch
constexpr float EPS_SUM = 256.0f * 1e-6f;

typedef __attribute__((ext_vector_type(8))) short bf16x8;
typedef __attribute__((ext_vector_type(4))) float f32x4;

__device__ __forceinline__ unsigned short bits(__hip_bfloat16 h) {
    union { __hip_bfloat16 b; unsigned short u; } cv;
    cv.b = h;
    return cv.u;
}

__device__ __forceinline__ float b2f(short s) {
    union { float f; unsigned u; } cv;
    cv.u = ((unsigned)(unsigned short)s) << 16;
    return cv.f;
}

// ----------------------------------------- convert (+ partial norms) -------
// grid = 1024 blocks (batch = blk&7 -> XCD-local), 256 threads.
// 64c x 64n tile: transpose, bf16 hi/lo split, atomic norm partial.
__global__ __launch_bounds__(256) void convert_kernel(const float* __restrict__ x,
                                                      __hip_bfloat16* __restrict__ hiT,
                                                      __hip_bfloat16* __restrict__ loT,
                                                      float* __restrict__ normacc) {
    const int blk = blockIdx.x;
    const int batch = blk & 7;
    const int nt = (blk >> 3) & 31;
    const int ctile = blk >> 8;
    const int n0 = nt << 6, c0 = ctile << 6;
    const int t = threadIdx.x;
    const int i = t & 63, j = t >> 6;

    __shared__ float tb[64][65];
    __shared__ float red[4][64];

    float s = 0.f;
    const float* xp = x + (size_t)batch * CN_ + (size_t)c0 * N_ + n0 + i;
#pragma unroll 4
    for (int r = 0; r < 16; ++r) {
        const int cl = j + r * 4;
        const float v = xp[(size_t)cl * N_];
        tb[cl][i] = v;
        s += v * v;
    }
    red[j][i] = s;
    __syncthreads();

    const int cp = t & 31;  // c-pair
    const int c2 = cp << 1;
    const int nb = t >> 5;  // 8 n-groups
#pragma unroll 4
    for (int r = 0; r < 8; ++r) {
        const int n = nb + r * 8;
        const float v0 = tb[c2][n], v1 = tb[c2 + 1][n];
        const size_t o = ((size_t)batch * N_ + n0 + n) * C_ + c0 + c2;
        const __hip_bfloat16 h0 = __float2bfloat16(v0);
        const __hip_bfloat16 h1 = __float2bfloat16(v1);
        const __hip_bfloat16 g0 = __float2bfloat16(v0 - __bfloat162float(h0));
        const __hip_bfloat16 g1 = __float2bfloat16(v1 - __bfloat162float(h1));
        ((unsigned*)hiT)[o >> 1] = ((unsigned)bits(h1) << 16) | bits(h0);
        ((unsigned*)loT)[o >> 1] = ((unsigned)bits(g1) << 16) | bits(g0);
    }
    if (j == 0) {
        const float tt = red[0][i] + red[1][i] + red[2][i] + red[3][i];
        atomicAdd(normacc + batch * N_ + n0 + i, tt);
    }
}

// ------------------------------- gram (MFMA, triangular) + argmax ----------
// grid = B * 136 blocks of 256 (4 waves); batch = blk & 7 (XCD-local L2).
// Barrier-free K-loop: each wave owns a 64x64 quadrant; A/B fragments are
// loaded global->VGPR (L2-hot), manually double-buffered. No LDS staging.
// sim = hi*hi + hi*lo + lo*hi (3 segs x 8 steps of K=32 = 24 steps).
__global__ __launch_bounds__(256, 3) void gram_mfma_kernel(
        const __hip_bfloat16* __restrict__ hiT, const __hip_bfloat16* __restrict__ loT,
        const float* __restrict__ normacc,
        float* __restrict__ pval, int* __restrict__ pidx, float* __restrict__ pval2) {
    const int blk = blockIdx.x;
    const int batch = blk & 7;
    int p = blk >> 3;  // 0..135
    int bn = 0;
    while (p >= NTILES - bn) { p -= NTILES - bn; ++bn; }
    const int bm = bn + p;
    const bool diag = (bn == bm);
    const int n0 = bn << 7, m0 = bm << 7;

    __shared__ float rv1[128][2];
    __shared__ int ri1[128][2];
    __shared__ float rv2[128][2];
    __shared__ float cv1[128][2];
    __shared__ int ci1[128][2];
    __shared__ float cv2[128][2];
    __shared__ float rnA[128];

    const int tid = threadIdx.x;
    const int l = tid & 63, w = tid >> 6;
    const int lm = l & 15, q = l >> 4;
    const int wn = (w >> 1) << 6, wm = (w & 1) << 6;

    f32x4 acc[4][4];
#pragma unroll
    for (int rt = 0; rt < 4; ++rt)
#pragma unroll
        for (int ct = 0; ct < 4; ++ct) acc[rt][ct] = (f32x4){0.f, 0.f, 0.f, 0.f};

    const size_t bbase = (size_t)batch * CN_;
    // per-lane element offsets of this lane's fragment row starts
    const size_t rowA = bbase + (size_t)(n0 + wn + lm) * C_ + q * 8;
    const size_t rowB = bbase + (size_t)(m0 + wm + lm) * C_ + q * 8;

    const short* const hs = (const short*)hiT;
    const short* const ls = (const short*)loT;

    bf16x8 a0[4], b0[4], a1[4], b1[4];

#define GRAM_LD(S, AF, BF)                                                  \
    {                                                                       \
        constexpr int seg_ = (S) >> 3, kt_ = (S) & 7;                       \
        const short* ap_ = ((seg_ == 2) ? ls : hs) + rowA + kt_ * 32;       \
        const short* bp_ = ((seg_ == 1) ? ls : hs) + rowB + kt_ * 32;       \
        _Pragma("unroll") for (int t_ = 0; t_ < 4; ++t_) {                  \
            AF[t_] = *(const bf16x8*)(ap_ + t_ * 16 * C_);                  \
            BF[t_] = *(const bf16x8*)(bp_ + t_ * 16 * C_);                  \
        }                                                                   \
    }

    GRAM_LD(0, a0, b0);
#pragma unroll
    for (int s = 0; s < 24; ++s) {
        bf16x8* ac = (s & 1) ? a1 : a0;
        bf16x8* bc = (s & 1) ? b1 : b0;
        bf16x8* an = (s & 1) ? a0 : a1;
        bf16x8* bn_ = (s & 1) ? b0 : b1;
        if (s + 1 < 24) {
            switch (s + 1) {
#define CASE_LD(SS) case SS: GRAM_LD(SS, an, bn_); break;
                CASE_LD(1) CASE_LD(2) CASE_LD(3) CASE_LD(4) CASE_LD(5)
                CASE_LD(6) CASE_LD(7) CASE_LD(8) CASE_LD(9) CASE_LD(10)
                CASE_LD(11) CASE_LD(12) CASE_LD(13) CASE_LD(14) CASE_LD(15)
                CASE_LD(16) CASE_LD(17) CASE_LD(18) CASE_LD(19) CASE_LD(20)
                CASE_LD(21) CASE_LD(22) CASE_LD(23)
#undef CASE_LD
            }
        }
#pragma unroll
        for (int rt = 0; rt < 4; ++rt)
#pragma unroll
            for (int ct = 0; ct < 4; ++ct)
                acc[rt][ct] = __builtin_amdgcn_mfma_f32_16x16x32_bf16(
                    ac[rt], bc[ct], acc[rt][ct], 0, 0, 0);
    }
#undef GRAM_LD

    if (tid < 128) rnA[tid] = 1.0f / sqrtf(normacc[batch * N_ + n0 + tid] + EPS_SUM);

    // ---- row path: rows n (n-strip), candidates m (m-strip), scale rnorm[m]
    float rnm[4];
#pragma unroll
    for (int ct = 0; ct < 4; ++ct)
        rnm[ct] = 1.0f / sqrtf(normacc[batch * N_ + m0 + wm + ct * 16 + lm] + EPS_SUM);

#pragma unroll
    for (int rt = 0; rt < 4; ++rt) {
#pragma unroll
        for (int r = 0; r < 4; ++r) {
            const int nrow = n0 + wn + rt * 16 + q * 4 + r;
            float v1 = -3.4e38f, v2 = -3.4e38f;
            int i1 = 0x7fffffff;
#pragma unroll
            for (int ct = 0; ct < 4; ++ct) {
                const int m = m0 + wm + ct * 16 + lm;
                const float v = acc[rt][ct][r] * rnm[ct];
                if (m == nrow) continue;
                if (v > v1) { v2 = v1; v1 = v; i1 = m; }
                else if (v > v2) v2 = v;
            }
#pragma unroll
            for (int d = 1; d < 16; d <<= 1) {
                const float ov1 = __shfl_xor(v1, d, 64);
                const int oi1 = __shfl_xor(i1, d, 64);
                const float ov2 = __shfl_xor(v2, d, 64);
                if (ov1 > v1 || (ov1 == v1 && oi1 < i1)) {
                    v2 = fmaxf(v1, ov2); v1 = ov1; i1 = oi1;
                } else {
                    v2 = fmaxf(v2, ov1);
                }
            }
            if (lm == 0) {
                const int rloc = wn + rt * 16 + q * 4 + r;
                rv1[rloc][w & 1] = v1;
                ri1[rloc][w & 1] = i1;
                rv2[rloc][w & 1] = v2;
            }
        }
    }
    __syncthreads();  // rnA + rv* visible

    // ---- col path: rows m (m-strip), candidates n (n-strip), scale rnorm[n]
    if (!diag) {
        float rnn[4][4];
#pragma unroll
        for (int rt = 0; rt < 4; ++rt)
#pragma unroll
            for (int r = 0; r < 4; ++r) rnn[rt][r] = rnA[wn + rt * 16 + q * 4 + r];
#pragma unroll
        for (int ct = 0; ct < 4; ++ct) {
            float v1 = -3.4e38f, v2 = -3.4e38f;
            int i1 = 0x7fffffff;
#pragma unroll
            for (int rt = 0; rt < 4; ++rt) {
#pragma unroll
                for (int r = 0; r < 4; ++r) {
                    const float v = acc[rt][ct][r] * rnn[rt][r];
                    const int nn = n0 + wn + rt * 16 + q * 4 + r;
                    if (v > v1) { v2 = v1; v1 = v; i1 = nn; }
                    else if (v > v2) v2 = v;
                }
            }
#pragma unroll
            for (int d = 16; d < 64; d <<= 1) {
                const float ov1 = __shfl_xor(v1, d, 64);
                const int oi1 = __shfl_xor(i1, d, 64);
                const float ov2 = __shfl_xor(v2, d, 64);
                if (ov1 > v1 || (ov1 == v1 && oi1 < i1)) {
                    v2 = fmaxf(v1, ov2); v1 = ov1; i1 = oi1;
                } else {
                    v2 = fmaxf(v2, ov1);
                }
            }
            if (q == 0) {
                const int mloc = wm + ct * 16 + lm;
                cv1[mloc][w >> 1] = v1;
                ci1[mloc][w >> 1] = i1;
                cv2[mloc][w >> 1] = v2;
            }
        }
    }
    __syncthreads();

    if (tid < 128) {
        // row result -> slot bm, rows n-strip
        {
            float v1 = rv1[tid][0]; int i1 = ri1[tid][0]; float v2 = rv2[tid][0];
            const float ov1 = rv1[tid][1]; const int oi1 = ri1[tid][1]; const float ov2 = rv2[tid][1];
            if (ov1 > v1 || (ov1 == v1 && oi1 < i1)) { v2 = fmaxf(v1, ov2); v1 = ov1; i1 = oi1; }
            else v2 = fmaxf(v2, ov1);
            const size_t gi = (size_t)(batch * NTILES + bm) * N_ + n0 + tid;
            pval[gi] = v1; pidx[gi] = i1; pval2[gi] = v2;
        }
        // col result -> slot bn, rows m-strip
        if (!diag) {
            float v1 = cv1[tid][0]; int i1 = ci1[tid][0]; float v2 = cv2[tid][0];
            const float ov1 = cv1[tid][1]; const int oi1 = ci1[tid][1]; const float ov2 = cv2[tid][1];
            if (ov1 > v1 || (ov1 == v1 && oi1 < i1)) { v2 = fmaxf(v1, ov2); v1 = ov1; i1 = oi1; }
            else v2 = fmaxf(v2, ov1);
            const size_t gi = (size_t)(batch * NTILES + bn) * N_ + m0 + tid;
            pval[gi] = v1; pidx[gi] = i1; pval2[gi] = v2;
        }
    }
}

// -------------------------------------------------------------- combine ----
__global__ void combine_kernel(const float* __restrict__ pval, const int* __restrict__ pidx,
                               const float* __restrict__ pval2, int* __restrict__ fidx,
                               int* __restrict__ rcnt, int* __restrict__ ridx) {
    const int t = blockIdx.x * 256 + threadIdx.x;  // 16384
    const int batch = t >> 11, n = t & 2047;
    float v1 = -3.4e38f, v2 = -3.4e38f;
    int i1 = 0x7fffffff;
    for (int s = 0; s < NTILES; ++s) {
        const size_t gi = (size_t)(batch * NTILES + s) * N_ + n;
        const float ov1 = pval[gi]; const int oi1 = pidx[gi]; const float ov2 = pval2[gi];
        if (ov1 > v1 || (ov1 == v1 && oi1 < i1)) { v2 = fmaxf(v1, ov2); v1 = ov1; i1 = oi1; }
        else v2 = fmaxf(v2, ov1);
    }
    fidx[t] = i1;
    if (v1 - v2 < 1e-4f) {
        const int slot = atomicAdd(rcnt, 1);
        ridx[slot] = t;
    }
}

// --------------------------------------------------------------- rescue ----
// Exact fp32 re-argmax for near-tie rows, reading original x (coalesced over m).
__global__ __launch_bounds__(256) void rescue_kernel(const float* __restrict__ x,
                                                     const float* __restrict__ normacc,
                                                     const int* __restrict__ rcnt,
                                                     const int* __restrict__ ridx,
                                                     int* __restrict__ fidx) {
    const int cnt = *rcnt;
    const int tid = threadIdx.x;
    __shared__ float bv[256];
    __shared__ int bi[256];
    for (int rr = blockIdx.x; rr < cnt; rr += gridDim.x) {
        const int t = ridx[rr];
        const int batch = t >> 11, n = t & 2047;
        const float* xb = x + (size_t)batch * CN_;
        float s[8];
#pragma unroll
        for (int k = 0; k < 8; ++k) s[k] = 0.f;
        for (int c = 0; c < C_; ++c) {
            const float xc = xb[(size_t)c * N_ + n];
            const float* xr = xb + (size_t)c * N_;
#pragma unroll
            for (int k = 0; k < 8; ++k) s[k] += xc * xr[tid + (k << 8)];
        }
        float best = -3.4e38f;
        int besti = 0x7fffffff;
#pragma unroll
        for (int k = 0; k < 8; ++k) {
            const int m = tid + (k << 8);
            const float v = s[k] / sqrtf(normacc[batch * N_ + m] + EPS_SUM);
            if (m != n && v > best) { best = v; besti = m; }
        }
        bv[tid] = best; bi[tid] = besti;
        __syncthreads();
        for (int sft = 128; sft > 0; sft >>= 1) {
            if (tid < sft) {
                const float ov = bv[tid + sft]; const int oi = bi[tid + sft];
                if (ov > bv[tid] || (ov == bv[tid] && oi < bi[tid])) { bv[tid] = ov; bi[tid] = oi; }
            }
            __syncthreads();
        }
        if (tid == 0) fidx[t] = bi[0];
        __syncthreads();
    }
}

// ------------------------------- finish: gate softmax + gather + outputs ---
// grid = 1024 blocks (batch = blk&7, 128 ntiles of 16 n), 256 threads.
__global__ __launch_bounds__(256) void finish_kernel(const float* __restrict__ x,
                                                     const __hip_bfloat16* __restrict__ hiT,
                                                     const __hip_bfloat16* __restrict__ loT,
                                                     const float* __restrict__ W,
                                                     const int* __restrict__ fidx,
                                                     float* __restrict__ out) {
    const int batch = blockIdx.x & 7;
    const int nt = blockIdx.x >> 3;  // 0..127
    const int n0 = nt << 4;
    const int t = threadIdx.x;
    const int i = t & 15, cg = t >> 4;  // cg 0..15, 16 c each

    __shared__ float Wl[1024];
    __shared__ int il[16];
    __shared__ float l0r[16][17], l1r[16][17];
    __shared__ float w0s[16], w1s[16];

    for (int u = t; u < 1024; u += 256) Wl[u] = W[u];
    if (t < 16) il[t] = fidx[batch * N_ + n0 + t];
    __syncthreads();

    const float* xb = x + (size_t)batch * CN_ + n0 + i;
    const int myidx = il[i];
    const size_t row = ((size_t)batch * N_ + myidx) * C_ + cg * 16;

    float fvv[16];
    {
        const bf16x8* hp = (const bf16x8*)(hiT + row);
        const bf16x8* lp = (const bf16x8*)(loT + row);
#pragma unroll
        for (int v8 = 0; v8 < 2; ++v8) {
            const bf16x8 h = hp[v8];
            const bf16x8 g = lp[v8];
#pragma unroll
            for (int e = 0; e < 8; ++e) fvv[v8 * 8 + e] = b2f(h[e]) + b2f(g[e]);
        }
    }

    float l0 = 0.f, l1 = 0.f;
#pragma unroll
    for (int cc = 0; cc < 16; ++cc) {
        const int c = cg * 16 + cc;
        const float xv = xb[(size_t)c * N_];
        l0 += xv * Wl[c] + fvv[cc] * Wl[256 + c];
        l1 += xv * Wl[512 + c] + fvv[cc] * Wl[768 + c];
    }
    l0r[cg][i] = l0;
    l1r[cg][i] = l1;
    __syncthreads();
    if (t < 16) {
        float L0 = 0.f, L1 = 0.f;
#pragma unroll
        for (int g = 0; g < 16; ++g) { L0 += l0r[g][t]; L1 += l1r[g][t]; }
        const float mx = fmaxf(L0, L1);
        const float e0 = expf(L0 - mx);
        const float e1 = expf(L1 - mx);
        const float inv = 1.0f / (e0 + e1);
        w0s[t] = e0 * inv;
        w1s[t] = e1 * inv;
    }
    __syncthreads();
    const float w0 = w0s[i], w1 = w1s[i];

#pragma unroll
    for (int cc = 0; cc < 16; ++cc) {
        const int c = cg * 16 + cc;
        const size_t off = (size_t)batch * CN_ + (size_t)c * N_ + n0 + i;
        const float xv = xb[(size_t)c * N_];  // L1-hot re-read
        out[off] = xv * w0 + fvv[cc] * w1;
        out[TOT_ + off] = fvv[cc];
    }
}

// ---------------------------------------------------------------------------
extern "C" void kernel_launch(void* const* d_in, const int* in_sizes, int n_in,
                              void* d_out, int out_size, void* d_ws, size_t ws_size,
                              hipStream_t stream) {
    const float* x = (const float*)d_in[0];
    const float* W = (const float*)d_in[1];
    float* out = (float*)d_out;

    const size_t BF_BYTES = (size_t)TOT_ * 2;             // 8.39 MB each
    const size_t NORM_BYTES = (size_t)B_ * N_ * 4;        // 64 KB
    const size_t P_BYTES = (size_t)B_ * NTILES * N_ * 4;  // 1 MB each

    uint8_t* p = (uint8_t*)d_ws;
    __hip_bfloat16* hiT = (__hip_bfloat16*)p; p += BF_BYTES;
    __hip_bfloat16* loT = (__hip_bfloat16*)p; p += BF_BYTES;
    float* normacc = (float*)p; p += NORM_BYTES;
    int* rcnt = (int*)p; p += 256;  // contiguous with normacc: single memset
    float* pval = (float*)p; p += P_BYTES;
    int* pidx = (int*)p; p += P_BYTES;
    float* pval2 = (float*)p; p += P_BYTES;
    int* fidx = (int*)p; p += NORM_BYTES;
    int* ridx = (int*)p; p += NORM_BYTES;

    hipMemsetAsync(normacc, 0, NORM_BYTES + 256, stream);
    convert_kernel<<<1024, 256, 0, stream>>>(x, hiT, loT, normacc);
    gram_mfma_kernel<<<B_ * NPAIRS, 256, 0, stream>>>(hiT, loT, normacc, pval, pidx, pval2);
    combine_kernel<<<64, 256, 0, stream>>>(pval, pidx, pval2, fidx, rcnt, ridx);
    rescue_kernel<<<64, 256, 0, stream>>>(x, normacc, rcnt, ridx, fidx);
    finish_kernel<<<1024, 256, 0, stream>>>(x, hiT, loT, W, fidx, out);
}

// Round 7
// 307.518 us; speedup vs baseline: 1.1481x; 1.1481x over previous
//
#include <hip/hip_runtime.h>
#include <hip/hip_bf16.h>
#include <math.h>

constexpr int B_ = 8;
constexpr int C_ = 256;
constexpr int N_ = 2048;
constexpr int CN_ = C_ * N_;        // 524288
constexpr int TOT_ = B_ * C_ * N_;  // 4194304
constexpr int NTILES = 16;          // 128-wide strips
constexpr int NPAIRS = 136;         // triangular tiles per batch
constexpr float EPS_SUM = 256.0f * 1e-6f;

typedef __attribute__((ext_vector_type(8))) short bf16x8;
typedef __attribute__((ext_vector_type(4))) float f32x4;

__device__ __forceinline__ unsigned short bits(__hip_bfloat16 h) {
    union { __hip_bfloat16 b; unsigned short u; } cv;
    cv.b = h;
    return cv.u;
}

__device__ __forceinline__ float b2f(short s) {
    union { float f; unsigned u; } cv;
    cv.u = ((unsigned)(unsigned short)s) << 16;
    return cv.f;
}

// ----------------------------------------- convert (+ partial norms) -------
__global__ __launch_bounds__(256) void convert_kernel(const float* __restrict__ x,
                                                      __hip_bfloat16* __restrict__ hiT,
                                                      __hip_bfloat16* __restrict__ loT,
                                                      float* __restrict__ normacc) {
    const int blk = blockIdx.x;
    const int batch = blk & 7;
    const int nt = (blk >> 3) & 31;
    const int ctile = blk >> 8;
    const int n0 = nt << 6, c0 = ctile << 6;
    const int t = threadIdx.x;
    const int i = t & 63, j = t >> 6;

    __shared__ float tb[64][65];
    __shared__ float red[4][64];

    float s = 0.f;
    const float* xp = x + (size_t)batch * CN_ + (size_t)c0 * N_ + n0 + i;
#pragma unroll 4
    for (int r = 0; r < 16; ++r) {
        const int cl = j + r * 4;
        const float v = xp[(size_t)cl * N_];
        tb[cl][i] = v;
        s += v * v;
    }
    red[j][i] = s;
    __syncthreads();

    const int cp = t & 31;
    const int c2 = cp << 1;
    const int nb = t >> 5;
#pragma unroll 4
    for (int r = 0; r < 8; ++r) {
        const int n = nb + r * 8;
        const float v0 = tb[c2][n], v1 = tb[c2 + 1][n];
        const size_t o = ((size_t)batch * N_ + n0 + n) * C_ + c0 + c2;
        const __hip_bfloat16 h0 = __float2bfloat16(v0);
        const __hip_bfloat16 h1 = __float2bfloat16(v1);
        const __hip_bfloat16 g0 = __float2bfloat16(v0 - __bfloat162float(h0));
        const __hip_bfloat16 g1 = __float2bfloat16(v1 - __bfloat162float(h1));
        ((unsigned*)hiT)[o >> 1] = ((unsigned)bits(h1) << 16) | bits(h0);
        ((unsigned*)loT)[o >> 1] = ((unsigned)bits(g1) << 16) | bits(g0);
    }
    if (j == 0) {
        const float tt = red[0][i] + red[1][i] + red[2][i] + red[3][i];
        atomicAdd(normacc + batch * N_ + n0 + i, tt);
    }
}

// ------------------------------- gram (MFMA, triangular) + argmax ----------
// grid = B * 136 blocks of 256 (4 waves); batch = blk & 7 (XCD-local L2).
// Barrier-free K-loop, fully unrolled even/odd register double-buffer:
// no pointer-to-array selection (that spilled in R6) — all step indices are
// literal constants. sim = hi*hi + hi*lo + lo*hi (24 steps of K=32).
__global__ __launch_bounds__(256, 2) void gram_mfma_kernel(
        const __hip_bfloat16* __restrict__ hiT, const __hip_bfloat16* __restrict__ loT,
        const float* __restrict__ normacc,
        float* __restrict__ pval, int* __restrict__ pidx, float* __restrict__ pval2) {
    const int blk = blockIdx.x;
    const int batch = blk & 7;
    int p = blk >> 3;  // 0..135
    int bn = 0;
    while (p >= NTILES - bn) { p -= NTILES - bn; ++bn; }
    const int bm = bn + p;
    const bool diag = (bn == bm);
    const int n0 = bn << 7, m0 = bm << 7;

    __shared__ float rv1[128][2];
    __shared__ int ri1[128][2];
    __shared__ float rv2[128][2];
    __shared__ float cv1[128][2];
    __shared__ int ci1[128][2];
    __shared__ float cv2[128][2];
    __shared__ float rnA[128];

    const int tid = threadIdx.x;
    const int l = tid & 63, w = tid >> 6;
    const int lm = l & 15, q = l >> 4;
    const int wn = (w >> 1) << 6, wm = (w & 1) << 6;

    f32x4 acc[4][4];
#pragma unroll
    for (int rt = 0; rt < 4; ++rt)
#pragma unroll
        for (int ct = 0; ct < 4; ++ct) acc[rt][ct] = (f32x4){0.f, 0.f, 0.f, 0.f};

    const size_t bbase = (size_t)batch * CN_;
    const size_t rowA = bbase + (size_t)(n0 + wn + lm) * C_ + q * 8;
    const size_t rowB = bbase + (size_t)(m0 + wm + lm) * C_ + q * 8;

    const short* const hs = (const short*)hiT;
    const short* const ls = (const short*)loT;

    bf16x8 a0[4], b0[4], a1[4], b1[4];

// literal-constant step load: seg = S>>3 (0:hi*hi 1:hi*lo 2:lo*hi), kt = S&7
#define GRAM_LD(S, AF, BF)                                                   \
    {                                                                        \
        constexpr int seg_ = (S) >> 3, kt_ = (S) & 7;                        \
        const short* ap_ = ((seg_ == 2) ? ls : hs) + rowA + kt_ * 32;        \
        const short* bp_ = ((seg_ == 1) ? ls : hs) + rowB + kt_ * 32;        \
        AF[0] = *(const bf16x8*)(ap_);                                       \
        AF[1] = *(const bf16x8*)(ap_ + 16 * C_);                             \
        AF[2] = *(const bf16x8*)(ap_ + 32 * C_);                             \
        AF[3] = *(const bf16x8*)(ap_ + 48 * C_);                             \
        BF[0] = *(const bf16x8*)(bp_);                                       \
        BF[1] = *(const bf16x8*)(bp_ + 16 * C_);                             \
        BF[2] = *(const bf16x8*)(bp_ + 32 * C_);                             \
        BF[3] = *(const bf16x8*)(bp_ + 48 * C_);                             \
    }

#define GRAM_MFMA(AF, BF)                                                    \
    _Pragma("unroll") for (int rt_ = 0; rt_ < 4; ++rt_)                      \
        _Pragma("unroll") for (int ct_ = 0; ct_ < 4; ++ct_)                  \
            acc[rt_][ct_] = __builtin_amdgcn_mfma_f32_16x16x32_bf16(         \
                AF[rt_], BF[ct_], acc[rt_][ct_], 0, 0, 0);

// consume step S (a0/b0) then prefetch S+2 into a0/b0; same for odd side
#define GRAM_STEP(S)            \
    GRAM_MFMA(a0, b0);          \
    GRAM_LD((S) + 2, a0, b0);   \
    GRAM_MFMA(a1, b1);          \
    GRAM_LD((S) + 3, a1, b1);

    GRAM_LD(0, a0, b0);
    GRAM_LD(1, a1, b1);
    GRAM_STEP(0)  GRAM_STEP(2)  GRAM_STEP(4)  GRAM_STEP(6)  GRAM_STEP(8)
    GRAM_STEP(10) GRAM_STEP(12) GRAM_STEP(14) GRAM_STEP(16) GRAM_STEP(18)
    GRAM_STEP(20)
    GRAM_MFMA(a0, b0);  // step 22
    GRAM_MFMA(a1, b1);  // step 23

#undef GRAM_STEP
#undef GRAM_MFMA
#undef GRAM_LD

    if (tid < 128) rnA[tid] = 1.0f / sqrtf(normacc[batch * N_ + n0 + tid] + EPS_SUM);

    // ---- row path: rows n (n-strip), candidates m (m-strip), scale rnorm[m]
    float rnm[4];
#pragma unroll
    for (int ct = 0; ct < 4; ++ct)
        rnm[ct] = 1.0f / sqrtf(normacc[batch * N_ + m0 + wm + ct * 16 + lm] + EPS_SUM);

#pragma unroll
    for (int rt = 0; rt < 4; ++rt) {
#pragma unroll
        for (int r = 0; r < 4; ++r) {
            const int nrow = n0 + wn + rt * 16 + q * 4 + r;
            float v1 = -3.4e38f, v2 = -3.4e38f;
            int i1 = 0x7fffffff;
#pragma unroll
            for (int ct = 0; ct < 4; ++ct) {
                const int m = m0 + wm + ct * 16 + lm;
                const float v = acc[rt][ct][r] * rnm[ct];
                if (m == nrow) continue;
                if (v > v1) { v2 = v1; v1 = v; i1 = m; }
                else if (v > v2) v2 = v;
            }
#pragma unroll
            for (int d = 1; d < 16; d <<= 1) {
                const float ov1 = __shfl_xor(v1, d, 64);
                const int oi1 = __shfl_xor(i1, d, 64);
                const float ov2 = __shfl_xor(v2, d, 64);
                if (ov1 > v1 || (ov1 == v1 && oi1 < i1)) {
                    v2 = fmaxf(v1, ov2); v1 = ov1; i1 = oi1;
                } else {
                    v2 = fmaxf(v2, ov1);
                }
            }
            if (lm == 0) {
                const int rloc = wn + rt * 16 + q * 4 + r;
                rv1[rloc][w & 1] = v1;
                ri1[rloc][w & 1] = i1;
                rv2[rloc][w & 1] = v2;
            }
        }
    }
    __syncthreads();  // rnA + rv* visible

    // ---- col path: rows m (m-strip), candidates n (n-strip), scale rnorm[n]
    if (!diag) {
        float rnn[4][4];
#pragma unroll
        for (int rt = 0; rt < 4; ++rt)
#pragma unroll
            for (int r = 0; r < 4; ++r) rnn[rt][r] = rnA[wn + rt * 16 + q * 4 + r];
#pragma unroll
        for (int ct = 0; ct < 4; ++ct) {
            float v1 = -3.4e38f, v2 = -3.4e38f;
            int i1 = 0x7fffffff;
#pragma unroll
            for (int rt = 0; rt < 4; ++rt) {
#pragma unroll
                for (int r = 0; r < 4; ++r) {
                    const float v = acc[rt][ct][r] * rnn[rt][r];
                    const int nn = n0 + wn + rt * 16 + q * 4 + r;
                    if (v > v1) { v2 = v1; v1 = v; i1 = nn; }
                    else if (v > v2) v2 = v;
                }
            }
#pragma unroll
            for (int d = 16; d < 64; d <<= 1) {
                const float ov1 = __shfl_xor(v1, d, 64);
                const int oi1 = __shfl_xor(i1, d, 64);
                const float ov2 = __shfl_xor(v2, d, 64);
                if (ov1 > v1 || (ov1 == v1 && oi1 < i1)) {
                    v2 = fmaxf(v1, ov2); v1 = ov1; i1 = oi1;
                } else {
                    v2 = fmaxf(v2, ov1);
                }
            }
            if (q == 0) {
                const int mloc = wm + ct * 16 + lm;
                cv1[mloc][w >> 1] = v1;
                ci1[mloc][w >> 1] = i1;
                cv2[mloc][w >> 1] = v2;
            }
        }
    }
    __syncthreads();

    if (tid < 128) {
        {
            float v1 = rv1[tid][0]; int i1 = ri1[tid][0]; float v2 = rv2[tid][0];
            const float ov1 = rv1[tid][1]; const int oi1 = ri1[tid][1]; const float ov2 = rv2[tid][1];
            if (ov1 > v1 || (ov1 == v1 && oi1 < i1)) { v2 = fmaxf(v1, ov2); v1 = ov1; i1 = oi1; }
            else v2 = fmaxf(v2, ov1);
            const size_t gi = (size_t)(batch * NTILES + bm) * N_ + n0 + tid;
            pval[gi] = v1; pidx[gi] = i1; pval2[gi] = v2;
        }
        if (!diag) {
            float v1 = cv1[tid][0]; int i1 = ci1[tid][0]; float v2 = cv2[tid][0];
            const float ov1 = cv1[tid][1]; const int oi1 = ci1[tid][1]; const float ov2 = cv2[tid][1];
            if (ov1 > v1 || (ov1 == v1 && oi1 < i1)) { v2 = fmaxf(v1, ov2); v1 = ov1; i1 = oi1; }
            else v2 = fmaxf(v2, ov1);
            const size_t gi = (size_t)(batch * NTILES + bn) * N_ + m0 + tid;
            pval[gi] = v1; pidx[gi] = i1; pval2[gi] = v2;
        }
    }
}

// -------------------------------------------------------------- combine ----
__global__ void combine_kernel(const float* __restrict__ pval, const int* __restrict__ pidx,
                               const float* __restrict__ pval2, int* __restrict__ fidx,
                               int* __restrict__ rcnt, int* __restrict__ ridx) {
    const int t = blockIdx.x * 256 + threadIdx.x;  // 16384
    const int batch = t >> 11, n = t & 2047;
    float v1 = -3.4e38f, v2 = -3.4e38f;
    int i1 = 0x7fffffff;
    for (int s = 0; s < NTILES; ++s) {
        const size_t gi = (size_t)(batch * NTILES + s) * N_ + n;
        const float ov1 = pval[gi]; const int oi1 = pidx[gi]; const float ov2 = pval2[gi];
        if (ov1 > v1 || (ov1 == v1 && oi1 < i1)) { v2 = fmaxf(v1, ov2); v1 = ov1; i1 = oi1; }
        else v2 = fmaxf(v2, ov1);
    }
    fidx[t] = i1;
    if (v1 - v2 < 1e-4f) {
        const int slot = atomicAdd(rcnt, 1);
        ridx[slot] = t;
    }
}

// --------------------------------------------------------------- rescue ----
__global__ __launch_bounds__(256) void rescue_kernel(const float* __restrict__ x,
                                                     const float* __restrict__ normacc,
                                                     const int* __restrict__ rcnt,
                                                     const int* __restrict__ ridx,
                                                     int* __restrict__ fidx) {
    const int cnt = *rcnt;
    const int tid = threadIdx.x;
    __shared__ float bv[256];
    __shared__ int bi[256];
    for (int rr = blockIdx.x; rr < cnt; rr += gridDim.x) {
        const int t = ridx[rr];
        const int batch = t >> 11, n = t & 2047;
        const float* xb = x + (size_t)batch * CN_;
        float s[8];
#pragma unroll
        for (int k = 0; k < 8; ++k) s[k] = 0.f;
        for (int c = 0; c < C_; ++c) {
            const float xc = xb[(size_t)c * N_ + n];
            const float* xr = xb + (size_t)c * N_;
#pragma unroll
            for (int k = 0; k < 8; ++k) s[k] += xc * xr[tid + (k << 8)];
        }
        float best = -3.4e38f;
        int besti = 0x7fffffff;
#pragma unroll
        for (int k = 0; k < 8; ++k) {
            const int m = tid + (k << 8);
            const float v = s[k] / sqrtf(normacc[batch * N_ + m] + EPS_SUM);
            if (m != n && v > best) { best = v; besti = m; }
        }
        bv[tid] = best; bi[tid] = besti;
        __syncthreads();
        for (int sft = 128; sft > 0; sft >>= 1) {
            if (tid < sft) {
                const float ov = bv[tid + sft]; const int oi = bi[tid + sft];
                if (ov > bv[tid] || (ov == bv[tid] && oi < bi[tid])) { bv[tid] = ov; bi[tid] = oi; }
            }
            __syncthreads();
        }
        if (tid == 0) fidx[t] = bi[0];
        __syncthreads();
    }
}

// ------------------------------- finish: gate softmax + gather + outputs ---
__global__ __launch_bounds__(256) void finish_kernel(const float* __restrict__ x,
                                                     const __hip_bfloat16* __restrict__ hiT,
                                                     const __hip_bfloat16* __restrict__ loT,
                                                     const float* __restrict__ W,
                                                     const int* __restrict__ fidx,
                                                     float* __restrict__ out) {
    const int batch = blockIdx.x & 7;
    const int nt = blockIdx.x >> 3;  // 0..127
    const int n0 = nt << 4;
    const int t = threadIdx.x;
    const int i = t & 15, cg = t >> 4;

    __shared__ float Wl[1024];
    __shared__ int il[16];
    __shared__ float l0r[16][17], l1r[16][17];
    __shared__ float w0s[16], w1s[16];

    for (int u = t; u < 1024; u += 256) Wl[u] = W[u];
    if (t < 16) il[t] = fidx[batch * N_ + n0 + t];
    __syncthreads();

    const float* xb = x + (size_t)batch * CN_ + n0 + i;
    const int myidx = il[i];
    const size_t row = ((size_t)batch * N_ + myidx) * C_ + cg * 16;

    float fvv[16];
    {
        const bf16x8* hp = (const bf16x8*)(hiT + row);
        const bf16x8* lp = (const bf16x8*)(loT + row);
#pragma unroll
        for (int v8 = 0; v8 < 2; ++v8) {
            const bf16x8 h = hp[v8];
            const bf16x8 g = lp[v8];
#pragma unroll
            for (int e = 0; e < 8; ++e) fvv[v8 * 8 + e] = b2f(h[e]) + b2f(g[e]);
        }
    }

    float l0 = 0.f, l1 = 0.f;
#pragma unroll
    for (int cc = 0; cc < 16; ++cc) {
        const int c = cg * 16 + cc;
        const float xv = xb[(size_t)c * N_];
        l0 += xv * Wl[c] + fvv[cc] * Wl[256 + c];
        l1 += xv * Wl[512 + c] + fvv[cc] * Wl[768 + c];
    }
    l0r[cg][i] = l0;
    l1r[cg][i] = l1;
    __syncthreads();
    if (t < 16) {
        float L0 = 0.f, L1 = 0.f;
#pragma unroll
        for (int g = 0; g < 16; ++g) { L0 += l0r[g][t]; L1 += l1r[g][t]; }
        const float mx = fmaxf(L0, L1);
        const float e0 = expf(L0 - mx);
        const float e1 = expf(L1 - mx);
        const float inv = 1.0f / (e0 + e1);
        w0s[t] = e0 * inv;
        w1s[t] = e1 * inv;
    }
    __syncthreads();
    const float w0 = w0s[i], w1 = w1s[i];

#pragma unroll
    for (int cc = 0; cc < 16; ++cc) {
        const int c = cg * 16 + cc;
        const size_t off = (size_t)batch * CN_ + (size_t)c * N_ + n0 + i;
        const float xv = xb[(size_t)c * N_];
        out[off] = xv * w0 + fvv[cc] * w1;
        out[TOT_ + off] = fvv[cc];
    }
}

// ---------------------------------------------------------------------------
extern "C" void kernel_launch(void* const* d_in, const int* in_sizes, int n_in,
                              void* d_out, int out_size, void* d_ws, size_t ws_size,
                              hipStream_t stream) {
    const float* x = (const float*)d_in[0];
    const float* W = (const float*)d_in[1];
    float* out = (float*)d_out;

    const size_t BF_BYTES = (size_t)TOT_ * 2;             // 8.39 MB each
    const size_t NORM_BYTES = (size_t)B_ * N_ * 4;        // 64 KB
    const size_t P_BYTES = (size_t)B_ * NTILES * N_ * 4;  // 1 MB each

    uint8_t* p = (uint8_t*)d_ws;
    __hip_bfloat16* hiT = (__hip_bfloat16*)p; p += BF_BYTES;
    __hip_bfloat16* loT = (__hip_bfloat16*)p; p += BF_BYTES;
    float* normacc = (float*)p; p += NORM_BYTES;
    int* rcnt = (int*)p; p += 256;  // contiguous with normacc: single memset
    float* pval = (float*)p; p += P_BYTES;
    int* pidx = (int*)p; p += P_BYTES;
    float* pval2 = (float*)p; p += P_BYTES;
    int* fidx = (int*)p; p += NORM_BYTES;
    int* ridx = (int*)p; p += NORM_BYTES;

    hipMemsetAsync(normacc, 0, NORM_BYTES + 256, stream);
    convert_kernel<<<1024, 256, 0, stream>>>(x, hiT, loT, normacc);
    gram_mfma_kernel<<<B_ * NPAIRS, 256, 0, stream>>>(hiT, loT, normacc, pval, pidx, pval2);
    combine_kernel<<<64, 256, 0, stream>>>(pval, pidx, pval2, fidx, rcnt, ridx);
    rescue_kernel<<<64, 256, 0, stream>>>(x, normacc, rcnt, ridx, fidx);
    finish_kernel<<<1024, 256, 0, stream>>>(x, hiT, loT, W, fidx, out);
}

// Round 8
// 258.320 us; speedup vs baseline: 1.3668x; 1.1905x over previous
//
#include <hip/hip_runtime.h>
#include <hip/hip_bf16.h>
#include <math.h>

constexpr int B_ = 8;
constexpr int C_ = 256;
constexpr int N_ = 2048;
constexpr int CN_ = C_ * N_;        // 524288
constexpr int TOT_ = B_ * C_ * N_;  // 4194304
constexpr int NTILES = 16;          // 128-wide strips
constexpr int NPAIRS = 136;         // triangular tiles per batch
constexpr float EPS_SUM = 256.0f * 1e-6f;

typedef __attribute__((ext_vector_type(8))) short bf16x8;
typedef __attribute__((ext_vector_type(4))) float f32x4;

__device__ __forceinline__ unsigned short bits(__hip_bfloat16 h) {
    union { __hip_bfloat16 b; unsigned short u; } cv;
    cv.b = h;
    return cv.u;
}

__device__ __forceinline__ float b2f(short s) {
    union { float f; unsigned u; } cv;
    cv.u = ((unsigned)(unsigned short)s) << 16;
    return cv.f;
}

// ----------------------------------------- convert (+ partial norms) -------
__global__ __launch_bounds__(256) void convert_kernel(const float* __restrict__ x,
                                                      __hip_bfloat16* __restrict__ hiT,
                                                      __hip_bfloat16* __restrict__ loT,
                                                      float* __restrict__ normacc) {
    const int blk = blockIdx.x;
    const int batch = blk & 7;
    const int nt = (blk >> 3) & 31;
    const int ctile = blk >> 8;
    const int n0 = nt << 6, c0 = ctile << 6;
    const int t = threadIdx.x;
    const int i = t & 63, j = t >> 6;

    __shared__ float tb[64][65];
    __shared__ float red[4][64];

    float s = 0.f;
    const float* xp = x + (size_t)batch * CN_ + (size_t)c0 * N_ + n0 + i;
#pragma unroll 4
    for (int r = 0; r < 16; ++r) {
        const int cl = j + r * 4;
        const float v = xp[(size_t)cl * N_];
        tb[cl][i] = v;
        s += v * v;
    }
    red[j][i] = s;
    __syncthreads();

    const int cp = t & 31;
    const int c2 = cp << 1;
    const int nb = t >> 5;
#pragma unroll 4
    for (int r = 0; r < 8; ++r) {
        const int n = nb + r * 8;
        const float v0 = tb[c2][n], v1 = tb[c2 + 1][n];
        const size_t o = ((size_t)batch * N_ + n0 + n) * C_ + c0 + c2;
        const __hip_bfloat16 h0 = __float2bfloat16(v0);
        const __hip_bfloat16 h1 = __float2bfloat16(v1);
        const __hip_bfloat16 g0 = __float2bfloat16(v0 - __bfloat162float(h0));
        const __hip_bfloat16 g1 = __float2bfloat16(v1 - __bfloat162float(h1));
        ((unsigned*)hiT)[o >> 1] = ((unsigned)bits(h1) << 16) | bits(h0);
        ((unsigned*)loT)[o >> 1] = ((unsigned)bits(g1) << 16) | bits(g0);
    }
    if (j == 0) {
        const float tt = red[0][i] + red[1][i] + red[2][i] + red[3][i];
        atomicAdd(normacc + batch * N_ + n0 + i, tt);
    }
}

// ------------------------------- gram (MFMA, triangular) + argmax ----------
// grid = B * 136 blocks of 256 (4 waves); batch = blk & 7 (XCD-local L2).
// Barrier-free K-loop, register double-buffer, ORDER-PINNED with
// sched_barrier(0) between every load/MFMA group so the scheduler cannot
// hoist loads across steps (R6/R7 spilled from exactly that hoisting).
// sim = hi*hi + hi*lo + lo*hi (24 steps of K=32).
__global__ __launch_bounds__(256, 2) void gram_mfma_kernel(
        const __hip_bfloat16* __restrict__ hiT, const __hip_bfloat16* __restrict__ loT,
        const float* __restrict__ normacc,
        float* __restrict__ pval, int* __restrict__ pidx, float* __restrict__ pval2) {
    const int blk = blockIdx.x;
    const int batch = blk & 7;
    int p = blk >> 3;  // 0..135
    int bn = 0;
    while (p >= NTILES - bn) { p -= NTILES - bn; ++bn; }
    const int bm = bn + p;
    const bool diag = (bn == bm);
    const int n0 = bn << 7, m0 = bm << 7;

    __shared__ float rv1[128][2];
    __shared__ int ri1[128][2];
    __shared__ float rv2[128][2];
    __shared__ float cv1[128][2];
    __shared__ int ci1[128][2];
    __shared__ float cv2[128][2];
    __shared__ float rnA[128];

    const int tid = threadIdx.x;
    const int l = tid & 63, w = tid >> 6;
    const int lm = l & 15, q = l >> 4;
    const int wn = (w >> 1) << 6, wm = (w & 1) << 6;

    f32x4 acc[4][4];
#pragma unroll
    for (int rt = 0; rt < 4; ++rt)
#pragma unroll
        for (int ct = 0; ct < 4; ++ct) acc[rt][ct] = (f32x4){0.f, 0.f, 0.f, 0.f};

    const size_t bbase = (size_t)batch * CN_;
    const size_t rowA = bbase + (size_t)(n0 + wn + lm) * C_ + q * 8;
    const size_t rowB = bbase + (size_t)(m0 + wm + lm) * C_ + q * 8;

    const short* const hs = (const short*)hiT;
    const short* const ls = (const short*)loT;

    bf16x8 a0[4], b0[4], a1[4], b1[4];

#define SB __builtin_amdgcn_sched_barrier(0)

// literal-constant step load: seg = S>>3 (0:hi*hi 1:hi*lo 2:lo*hi), kt = S&7
#define GRAM_LD(S, AF, BF)                                                   \
    {                                                                        \
        constexpr int seg_ = (S) >> 3, kt_ = (S) & 7;                        \
        const short* ap_ = ((seg_ == 2) ? ls : hs) + rowA + kt_ * 32;        \
        const short* bp_ = ((seg_ == 1) ? ls : hs) + rowB + kt_ * 32;        \
        AF[0] = *(const bf16x8*)(ap_);                                       \
        AF[1] = *(const bf16x8*)(ap_ + 16 * C_);                             \
        AF[2] = *(const bf16x8*)(ap_ + 32 * C_);                             \
        AF[3] = *(const bf16x8*)(ap_ + 48 * C_);                             \
        BF[0] = *(const bf16x8*)(bp_);                                       \
        BF[1] = *(const bf16x8*)(bp_ + 16 * C_);                             \
        BF[2] = *(const bf16x8*)(bp_ + 32 * C_);                             \
        BF[3] = *(const bf16x8*)(bp_ + 48 * C_);                             \
    }

#define GRAM_MFMA(AF, BF)                                                    \
    _Pragma("unroll") for (int rt_ = 0; rt_ < 4; ++rt_)                      \
        _Pragma("unroll") for (int ct_ = 0; ct_ < 4; ++ct_)                  \
            acc[rt_][ct_] = __builtin_amdgcn_mfma_f32_16x16x32_bf16(         \
                AF[rt_], BF[ct_], acc[rt_][ct_], 0, 0, 0);

// pinned pipeline step: consume a0 -> refill a0 (S+2) -> consume a1 -> refill a1 (S+3)
#define GRAM_STEP(S)                       \
    GRAM_MFMA(a0, b0); SB;                 \
    GRAM_LD((S) + 2, a0, b0); SB;          \
    GRAM_MFMA(a1, b1); SB;                 \
    GRAM_LD((S) + 3, a1, b1); SB;

    GRAM_LD(0, a0, b0); SB;
    GRAM_LD(1, a1, b1); SB;
    GRAM_STEP(0)  GRAM_STEP(2)  GRAM_STEP(4)  GRAM_STEP(6)  GRAM_STEP(8)
    GRAM_STEP(10) GRAM_STEP(12) GRAM_STEP(14) GRAM_STEP(16) GRAM_STEP(18)
    GRAM_STEP(20)
    GRAM_MFMA(a0, b0); SB;  // step 22
    GRAM_MFMA(a1, b1); SB;  // step 23

#undef GRAM_STEP
#undef GRAM_MFMA
#undef GRAM_LD
#undef SB

    if (tid < 128) rnA[tid] = 1.0f / sqrtf(normacc[batch * N_ + n0 + tid] + EPS_SUM);

    // ---- row path: rows n (n-strip), candidates m (m-strip), scale rnorm[m]
    float rnm[4];
#pragma unroll
    for (int ct = 0; ct < 4; ++ct)
        rnm[ct] = 1.0f / sqrtf(normacc[batch * N_ + m0 + wm + ct * 16 + lm] + EPS_SUM);

#pragma unroll
    for (int rt = 0; rt < 4; ++rt) {
#pragma unroll
        for (int r = 0; r < 4; ++r) {
            const int nrow = n0 + wn + rt * 16 + q * 4 + r;
            float v1 = -3.4e38f, v2 = -3.4e38f;
            int i1 = 0x7fffffff;
#pragma unroll
            for (int ct = 0; ct < 4; ++ct) {
                const int m = m0 + wm + ct * 16 + lm;
                const float v = acc[rt][ct][r] * rnm[ct];
                if (m == nrow) continue;
                if (v > v1) { v2 = v1; v1 = v; i1 = m; }
                else if (v > v2) v2 = v;
            }
#pragma unroll
            for (int d = 1; d < 16; d <<= 1) {
                const float ov1 = __shfl_xor(v1, d, 64);
                const int oi1 = __shfl_xor(i1, d, 64);
                const float ov2 = __shfl_xor(v2, d, 64);
                if (ov1 > v1 || (ov1 == v1 && oi1 < i1)) {
                    v2 = fmaxf(v1, ov2); v1 = ov1; i1 = oi1;
                } else {
                    v2 = fmaxf(v2, ov1);
                }
            }
            if (lm == 0) {
                const int rloc = wn + rt * 16 + q * 4 + r;
                rv1[rloc][w & 1] = v1;
                ri1[rloc][w & 1] = i1;
                rv2[rloc][w & 1] = v2;
            }
        }
    }
    __syncthreads();  // rnA + rv* visible

    // ---- col path: rows m (m-strip), candidates n (n-strip), scale rnorm[n]
    if (!diag) {
        float rnn[4][4];
#pragma unroll
        for (int rt = 0; rt < 4; ++rt)
#pragma unroll
            for (int r = 0; r < 4; ++r) rnn[rt][r] = rnA[wn + rt * 16 + q * 4 + r];
#pragma unroll
        for (int ct = 0; ct < 4; ++ct) {
            float v1 = -3.4e38f, v2 = -3.4e38f;
            int i1 = 0x7fffffff;
#pragma unroll
            for (int rt = 0; rt < 4; ++rt) {
#pragma unroll
                for (int r = 0; r < 4; ++r) {
                    const float v = acc[rt][ct][r] * rnn[rt][r];
                    const int nn = n0 + wn + rt * 16 + q * 4 + r;
                    if (v > v1) { v2 = v1; v1 = v; i1 = nn; }
                    else if (v > v2) v2 = v;
                }
            }
#pragma unroll
            for (int d = 16; d < 64; d <<= 1) {
                const float ov1 = __shfl_xor(v1, d, 64);
                const int oi1 = __shfl_xor(i1, d, 64);
                const float ov2 = __shfl_xor(v2, d, 64);
                if (ov1 > v1 || (ov1 == v1 && oi1 < i1)) {
                    v2 = fmaxf(v1, ov2); v1 = ov1; i1 = oi1;
                } else {
                    v2 = fmaxf(v2, ov1);
                }
            }
            if (q == 0) {
                const int mloc = wm + ct * 16 + lm;
                cv1[mloc][w >> 1] = v1;
                ci1[mloc][w >> 1] = i1;
                cv2[mloc][w >> 1] = v2;
            }
        }
    }
    __syncthreads();

    if (tid < 128) {
        {
            float v1 = rv1[tid][0]; int i1 = ri1[tid][0]; float v2 = rv2[tid][0];
            const float ov1 = rv1[tid][1]; const int oi1 = ri1[tid][1]; const float ov2 = rv2[tid][1];
            if (ov1 > v1 || (ov1 == v1 && oi1 < i1)) { v2 = fmaxf(v1, ov2); v1 = ov1; i1 = oi1; }
            else v2 = fmaxf(v2, ov1);
            const size_t gi = (size_t)(batch * NTILES + bm) * N_ + n0 + tid;
            pval[gi] = v1; pidx[gi] = i1; pval2[gi] = v2;
        }
        if (!diag) {
            float v1 = cv1[tid][0]; int i1 = ci1[tid][0]; float v2 = cv2[tid][0];
            const float ov1 = cv1[tid][1]; const int oi1 = ci1[tid][1]; const float ov2 = cv2[tid][1];
            if (ov1 > v1 || (ov1 == v1 && oi1 < i1)) { v2 = fmaxf(v1, ov2); v1 = ov1; i1 = oi1; }
            else v2 = fmaxf(v2, ov1);
            const size_t gi = (size_t)(batch * NTILES + bn) * N_ + m0 + tid;
            pval[gi] = v1; pidx[gi] = i1; pval2[gi] = v2;
        }
    }
}

// -------------------------------------------------------------- combine ----
__global__ void combine_kernel(const float* __restrict__ pval, const int* __restrict__ pidx,
                               const float* __restrict__ pval2, int* __restrict__ fidx,
                               int* __restrict__ rcnt, int* __restrict__ ridx) {
    const int t = blockIdx.x * 256 + threadIdx.x;  // 16384
    const int batch = t >> 11, n = t & 2047;
    float v1 = -3.4e38f, v2 = -3.4e38f;
    int i1 = 0x7fffffff;
    for (int s = 0; s < NTILES; ++s) {
        const size_t gi = (size_t)(batch * NTILES + s) * N_ + n;
        const float ov1 = pval[gi]; const int oi1 = pidx[gi]; const float ov2 = pval2[gi];
        if (ov1 > v1 || (ov1 == v1 && oi1 < i1)) { v2 = fmaxf(v1, ov2); v1 = ov1; i1 = oi1; }
        else v2 = fmaxf(v2, ov1);
    }
    fidx[t] = i1;
    if (v1 - v2 < 1e-4f) {
        const int slot = atomicAdd(rcnt, 1);
        ridx[slot] = t;
    }
}

// --------------------------------------------------------------- rescue ----
__global__ __launch_bounds__(256) void rescue_kernel(const float* __restrict__ x,
                                                     const float* __restrict__ normacc,
                                                     const int* __restrict__ rcnt,
                                                     const int* __restrict__ ridx,
                                                     int* __restrict__ fidx) {
    const int cnt = *rcnt;
    const int tid = threadIdx.x;
    __shared__ float bv[256];
    __shared__ int bi[256];
    for (int rr = blockIdx.x; rr < cnt; rr += gridDim.x) {
        const int t = ridx[rr];
        const int batch = t >> 11, n = t & 2047;
        const float* xb = x + (size_t)batch * CN_;
        float s[8];
#pragma unroll
        for (int k = 0; k < 8; ++k) s[k] = 0.f;
        for (int c = 0; c < C_; ++c) {
            const float xc = xb[(size_t)c * N_ + n];
            const float* xr = xb + (size_t)c * N_;
#pragma unroll
            for (int k = 0; k < 8; ++k) s[k] += xc * xr[tid + (k << 8)];
        }
        float best = -3.4e38f;
        int besti = 0x7fffffff;
#pragma unroll
        for (int k = 0; k < 8; ++k) {
            const int m = tid + (k << 8);
            const float v = s[k] / sqrtf(normacc[batch * N_ + m] + EPS_SUM);
            if (m != n && v > best) { best = v; besti = m; }
        }
        bv[tid] = best; bi[tid] = besti;
        __syncthreads();
        for (int sft = 128; sft > 0; sft >>= 1) {
            if (tid < sft) {
                const float ov = bv[tid + sft]; const int oi = bi[tid + sft];
                if (ov > bv[tid] || (ov == bv[tid] && oi < bi[tid])) { bv[tid] = ov; bi[tid] = oi; }
            }
            __syncthreads();
        }
        if (tid == 0) fidx[t] = bi[0];
        __syncthreads();
    }
}

// ------------------------------- finish: gate softmax + gather + outputs ---
__global__ __launch_bounds__(256) void finish_kernel(const float* __restrict__ x,
                                                     const __hip_bfloat16* __restrict__ hiT,
                                                     const __hip_bfloat16* __restrict__ loT,
                                                     const float* __restrict__ W,
                                                     const int* __restrict__ fidx,
                                                     float* __restrict__ out) {
    const int batch = blockIdx.x & 7;
    const int nt = blockIdx.x >> 3;  // 0..127
    const int n0 = nt << 4;
    const int t = threadIdx.x;
    const int i = t & 15, cg = t >> 4;

    __shared__ float Wl[1024];
    __shared__ int il[16];
    __shared__ float l0r[16][17], l1r[16][17];
    __shared__ float w0s[16], w1s[16];

    for (int u = t; u < 1024; u += 256) Wl[u] = W[u];
    if (t < 16) il[t] = fidx[batch * N_ + n0 + t];
    __syncthreads();

    const float* xb = x + (size_t)batch * CN_ + n0 + i;
    const int myidx = il[i];
    const size_t row = ((size_t)batch * N_ + myidx) * C_ + cg * 16;

    float fvv[16];
    {
        const bf16x8* hp = (const bf16x8*)(hiT + row);
        const bf16x8* lp = (const bf16x8*)(loT + row);
#pragma unroll
        for (int v8 = 0; v8 < 2; ++v8) {
            const bf16x8 h = hp[v8];
            const bf16x8 g = lp[v8];
#pragma unroll
            for (int e = 0; e < 8; ++e) fvv[v8 * 8 + e] = b2f(h[e]) + b2f(g[e]);
        }
    }

    float l0 = 0.f, l1 = 0.f;
#pragma unroll
    for (int cc = 0; cc < 16; ++cc) {
        const int c = cg * 16 + cc;
        const float xv = xb[(size_t)c * N_];
        l0 += xv * Wl[c] + fvv[cc] * Wl[256 + c];
        l1 += xv * Wl[512 + c] + fvv[cc] * Wl[768 + c];
    }
    l0r[cg][i] = l0;
    l1r[cg][i] = l1;
    __syncthreads();
    if (t < 16) {
        float L0 = 0.f, L1 = 0.f;
#pragma unroll
        for (int g = 0; g < 16; ++g) { L0 += l0r[g][t]; L1 += l1r[g][t]; }
        const float mx = fmaxf(L0, L1);
        const float e0 = expf(L0 - mx);
        const float e1 = expf(L1 - mx);
        const float inv = 1.0f / (e0 + e1);
        w0s[t] = e0 * inv;
        w1s[t] = e1 * inv;
    }
    __syncthreads();
    const float w0 = w0s[i], w1 = w1s[i];

#pragma unroll
    for (int cc = 0; cc < 16; ++cc) {
        const int c = cg * 16 + cc;
        const size_t off = (size_t)batch * CN_ + (size_t)c * N_ + n0 + i;
        const float xv = xb[(size_t)c * N_];
        out[off] = xv * w0 + fvv[cc] * w1;
        out[TOT_ + off] = fvv[cc];
    }
}

// ---------------------------------------------------------------------------
extern "C" void kernel_launch(void* const* d_in, const int* in_sizes, int n_in,
                              void* d_out, int out_size, void* d_ws, size_t ws_size,
                              hipStream_t stream) {
    const float* x = (const float*)d_in[0];
    const float* W = (const float*)d_in[1];
    float* out = (float*)d_out;

    const size_t BF_BYTES = (size_t)TOT_ * 2;             // 8.39 MB each
    const size_t NORM_BYTES = (size_t)B_ * N_ * 4;        // 64 KB
    const size_t P_BYTES = (size_t)B_ * NTILES * N_ * 4;  // 1 MB each

    uint8_t* p = (uint8_t*)d_ws;
    __hip_bfloat16* hiT = (__hip_bfloat16*)p; p += BF_BYTES;
    __hip_bfloat16* loT = (__hip_bfloat16*)p; p += BF_BYTES;
    float* normacc = (float*)p; p += NORM_BYTES;
    int* rcnt = (int*)p; p += 256;  // contiguous with normacc: single memset
    float* pval = (float*)p; p += P_BYTES;
    int* pidx = (int*)p; p += P_BYTES;
    float* pval2 = (float*)p; p += P_BYTES;
    int* fidx = (int*)p; p += NORM_BYTES;
    int* ridx = (int*)p; p += NORM_BYTES;

    hipMemsetAsync(normacc, 0, NORM_BYTES + 256, stream);
    convert_kernel<<<1024, 256, 0, stream>>>(x, hiT, loT, normacc);
    gram_mfma_kernel<<<B_ * NPAIRS, 256, 0, stream>>>(hiT, loT, normacc, pval, pidx, pval2);
    combine_kernel<<<64, 256, 0, stream>>>(pval, pidx, pval2, fidx, rcnt, ridx);
    rescue_kernel<<<64, 256, 0, stream>>>(x, normacc, rcnt, ridx, fidx);
    finish_kernel<<<1024, 256, 0, stream>>>(x, hiT, loT, W, fidx, out);
}

// Round 9
// 224.098 us; speedup vs baseline: 1.5755x; 1.1527x over previous
//
#include <hip/hip_runtime.h>
#include <hip/hip_bf16.h>
#include <math.h>

constexpr int B_ = 8;
constexpr int C_ = 256;
constexpr int N_ = 2048;
constexpr int CN_ = C_ * N_;        // 524288
constexpr int TOT_ = B_ * C_ * N_;  // 4194304
constexpr int BN_ = B_ * N_;        // 16384
constexpr int NTILES = 16;          // 128-wide strips
constexpr int NPAIRS = 136;         // triangular tiles per batch
constexpr float EPS_SUM = 256.0f * 1e-6f;

typedef __attribute__((ext_vector_type(8))) short bf16x8;
typedef __attribute__((ext_vector_type(4))) float f32x4;

__device__ __forceinline__ void g2l16(const void* g, void* l) {
    __builtin_amdgcn_global_load_lds(
        (const __attribute__((address_space(1))) void*)g,
        (__attribute__((address_space(3))) void*)l, 16, 0, 0);
}

__device__ __forceinline__ unsigned short bits(__hip_bfloat16 h) {
    union { __hip_bfloat16 b; unsigned short u; } cv;
    cv.b = h;
    return cv.u;
}

__device__ __forceinline__ float b2f(short s) {
    union { float f; unsigned u; } cv;
    cv.u = ((unsigned)(unsigned short)s) << 16;
    return cv.f;
}

// sum of 4 per-ctile norm partials -> reciprocal norm
__device__ __forceinline__ float rnorm_at(const float* __restrict__ np, int idx) {
    return 1.0f / sqrtf(np[idx] + np[BN_ + idx] + np[2 * BN_ + idx] +
                        np[3 * BN_ + idx] + EPS_SUM);
}

// ----------------------------------------- convert (+ norm partials) -------
// grid = 1024 blocks, 256 threads. 64c x 64n tile: transpose, bf16 hi/lo
// split, per-ctile norm partial (no atomics, no memset). Block 0 zeroes rcnt.
__global__ __launch_bounds__(256) void convert_kernel(const float* __restrict__ x,
                                                      __hip_bfloat16* __restrict__ hiT,
                                                      __hip_bfloat16* __restrict__ loT,
                                                      float* __restrict__ normpart,
                                                      int* __restrict__ rcnt) {
    const int blk = blockIdx.x;
    const int nt = blk & 31, ctile = (blk >> 5) & 3, batch = blk >> 7;
    const int n0 = nt << 6, c0 = ctile << 6;
    const int t = threadIdx.x;
    const int i = t & 63, j = t >> 6;

    if (blk == 0 && t == 0) *rcnt = 0;

    __shared__ float tb[64][65];
    __shared__ float red[4][64];

    float s = 0.f;
    const float* xp = x + (size_t)batch * CN_ + (size_t)c0 * N_ + n0 + i;
#pragma unroll 4
    for (int r = 0; r < 16; ++r) {
        const int cl = j + r * 4;
        const float v = xp[(size_t)cl * N_];
        tb[cl][i] = v;
        s += v * v;
    }
    red[j][i] = s;
    __syncthreads();

    const int cp = t & 31;
    const int c2 = cp << 1;
    const int nb = t >> 5;
#pragma unroll 4
    for (int r = 0; r < 8; ++r) {
        const int n = nb + r * 8;
        const float v0 = tb[c2][n], v1 = tb[c2 + 1][n];
        const size_t o = ((size_t)batch * N_ + n0 + n) * C_ + c0 + c2;
        const __hip_bfloat16 h0 = __float2bfloat16(v0);
        const __hip_bfloat16 h1 = __float2bfloat16(v1);
        const __hip_bfloat16 g0 = __float2bfloat16(v0 - __bfloat162float(h0));
        const __hip_bfloat16 g1 = __float2bfloat16(v1 - __bfloat162float(h1));
        ((unsigned*)hiT)[o >> 1] = ((unsigned)bits(h1) << 16) | bits(h0);
        ((unsigned*)loT)[o >> 1] = ((unsigned)bits(g1) << 16) | bits(g0);
    }
    if (j == 0) {
        const float tt = red[0][i] + red[1][i] + red[2][i] + red[3][i];
        normpart[ctile * BN_ + batch * N_ + n0 + i] = tt;
    }
}

// ------------------------------- gram (MFMA, triangular) + argmax ----------
// grid = B * 136 blocks of 256 (4 waves); batch = blk / NPAIRS (R4 mapping —
// fastest measured; XCD-swizzle variants were slower). 128x128 tile, BK=64,
// XOR-swizzled LDS staging via global_load_lds. Epilogue arrays overlay As
// (LDS 32 KB -> 5 blocks/CU). sim = hi*hi + hi*lo + lo*hi.
__global__ __launch_bounds__(256) void gram_mfma_kernel(
        const __hip_bfloat16* __restrict__ hiT, const __hip_bfloat16* __restrict__ loT,
        const float* __restrict__ normpart,
        float* __restrict__ pval, int* __restrict__ pidx, float* __restrict__ pval2) {
    const int blk = blockIdx.x;
    const int batch = blk / NPAIRS;
    int p = blk - batch * NPAIRS;
    int bn = 0;
    while (p >= NTILES - bn) { p -= NTILES - bn; ++bn; }
    const int bm = bn + p;
    const bool diag = (bn == bm);
    const int n0 = bn << 7, m0 = bm << 7;

    __shared__ short As[128 * 64];
    __shared__ short Bs[128 * 64];
    // epilogue arrays overlaid on As (used only after post-K-loop barrier)
    float (*rv1)[2] = (float(*)[2])(As + 0);
    int (*ri1)[2] = (int(*)[2])(As + 512);
    float (*rv2)[2] = (float(*)[2])(As + 1024);
    float (*cv1)[2] = (float(*)[2])(As + 1536);
    int (*ci1)[2] = (int(*)[2])(As + 2048);
    float (*cv2)[2] = (float(*)[2])(As + 2560);
    float* rnA = (float*)(As + 3072);

    const int tid = threadIdx.x;
    const int l = tid & 63, w = tid >> 6;
    const int lm = l & 15, q = l >> 4;
    const int wn = (w >> 1) << 6, wm = (w & 1) << 6;

    f32x4 acc[4][4];
#pragma unroll
    for (int rt = 0; rt < 4; ++rt)
#pragma unroll
        for (int ct = 0; ct < 4; ++ct) acc[rt][ct] = (f32x4){0.f, 0.f, 0.f, 0.f};

    const size_t bbase = (size_t)batch * CN_;

    for (int seg = 0; seg < 3; ++seg) {
        const __hip_bfloat16* Asrc = (seg == 2) ? loT : hiT;
        const __hip_bfloat16* Bsrc = (seg == 1) ? loT : hiT;
        for (int kt = 0; kt < 4; ++kt) {
            const int kb = kt << 6;
            __syncthreads();
#pragma unroll
            for (int pp = 0; pp < 4; ++pp) {
                const int slot = tid + pp * 256;
                const int r = slot >> 3, sidx = slot & 7;
                const int sw = sidx ^ (r & 7);  // XOR swizzle (self-inverse)
                g2l16(Asrc + bbase + (size_t)(n0 + r) * C_ + kb + sw * 8, As + slot * 8);
                g2l16(Bsrc + bbase + (size_t)(m0 + r) * C_ + kb + sw * 8, Bs + slot * 8);
            }
            __syncthreads();
#pragma unroll
            for (int kq = 0; kq < 2; ++kq) {
                bf16x8 af[4], bfr[4];
#pragma unroll
                for (int rt = 0; rt < 4; ++rt) {
                    const int row = wn + rt * 16 + lm;
                    af[rt] = *(const bf16x8*)(As + row * 64 + (((kq << 2) | q) ^ (lm & 7)) * 8);
                }
#pragma unroll
                for (int ct = 0; ct < 4; ++ct) {
                    const int row = wm + ct * 16 + lm;
                    bfr[ct] = *(const bf16x8*)(Bs + row * 64 + (((kq << 2) | q) ^ (lm & 7)) * 8);
                }
#pragma unroll
                for (int rt = 0; rt < 4; ++rt)
#pragma unroll
                    for (int ct = 0; ct < 4; ++ct)
                        acc[rt][ct] = __builtin_amdgcn_mfma_f32_16x16x32_bf16(
                            af[rt], bfr[ct], acc[rt][ct], 0, 0, 0);
            }
        }
    }

    __syncthreads();  // drain all LDS reads before overlaying As
    if (tid < 128) rnA[tid] = rnorm_at(normpart, batch * N_ + n0 + tid);

    // ---- row path: rows n (n-strip), candidates m (m-strip), scale rnorm[m]
    float rnm[4];
#pragma unroll
    for (int ct = 0; ct < 4; ++ct)
        rnm[ct] = rnorm_at(normpart, batch * N_ + m0 + wm + ct * 16 + lm);

#pragma unroll
    for (int rt = 0; rt < 4; ++rt) {
#pragma unroll
        for (int r = 0; r < 4; ++r) {
            const int nrow = n0 + wn + rt * 16 + q * 4 + r;
            float v1 = -3.4e38f, v2 = -3.4e38f;
            int i1 = 0x7fffffff;
#pragma unroll
            for (int ct = 0; ct < 4; ++ct) {
                const int m = m0 + wm + ct * 16 + lm;
                const float v = acc[rt][ct][r] * rnm[ct];
                if (m == nrow) continue;
                if (v > v1) { v2 = v1; v1 = v; i1 = m; }
                else if (v > v2) v2 = v;
            }
#pragma unroll
            for (int d = 1; d < 16; d <<= 1) {
                const float ov1 = __shfl_xor(v1, d, 64);
                const int oi1 = __shfl_xor(i1, d, 64);
                const float ov2 = __shfl_xor(v2, d, 64);
                if (ov1 > v1 || (ov1 == v1 && oi1 < i1)) {
                    v2 = fmaxf(v1, ov2); v1 = ov1; i1 = oi1;
                } else {
                    v2 = fmaxf(v2, ov1);
                }
            }
            if (lm == 0) {
                const int rloc = wn + rt * 16 + q * 4 + r;
                rv1[rloc][w & 1] = v1;
                ri1[rloc][w & 1] = i1;
                rv2[rloc][w & 1] = v2;
            }
        }
    }
    __syncthreads();  // rnA + rv* visible

    // ---- col path: rows m (m-strip), candidates n (n-strip), scale rnorm[n]
    if (!diag) {
        float rnn[4][4];
#pragma unroll
        for (int rt = 0; rt < 4; ++rt)
#pragma unroll
            for (int r = 0; r < 4; ++r) rnn[rt][r] = rnA[wn + rt * 16 + q * 4 + r];
#pragma unroll
        for (int ct = 0; ct < 4; ++ct) {
            float v1 = -3.4e38f, v2 = -3.4e38f;
            int i1 = 0x7fffffff;
#pragma unroll
            for (int rt = 0; rt < 4; ++rt) {
#pragma unroll
                for (int r = 0; r < 4; ++r) {
                    const float v = acc[rt][ct][r] * rnn[rt][r];
                    const int nn = n0 + wn + rt * 16 + q * 4 + r;
                    if (v > v1) { v2 = v1; v1 = v; i1 = nn; }
                    else if (v > v2) v2 = v;
                }
            }
#pragma unroll
            for (int d = 16; d < 64; d <<= 1) {
                const float ov1 = __shfl_xor(v1, d, 64);
                const int oi1 = __shfl_xor(i1, d, 64);
                const float ov2 = __shfl_xor(v2, d, 64);
                if (ov1 > v1 || (ov1 == v1 && oi1 < i1)) {
                    v2 = fmaxf(v1, ov2); v1 = ov1; i1 = oi1;
                } else {
                    v2 = fmaxf(v2, ov1);
                }
            }
            if (q == 0) {
                const int mloc = wm + ct * 16 + lm;
                cv1[mloc][w >> 1] = v1;
                ci1[mloc][w >> 1] = i1;
                cv2[mloc][w >> 1] = v2;
            }
        }
    }
    __syncthreads();

    if (tid < 128) {
        {
            float v1 = rv1[tid][0]; int i1 = ri1[tid][0]; float v2 = rv2[tid][0];
            const float ov1 = rv1[tid][1]; const int oi1 = ri1[tid][1]; const float ov2 = rv2[tid][1];
            if (ov1 > v1 || (ov1 == v1 && oi1 < i1)) { v2 = fmaxf(v1, ov2); v1 = ov1; i1 = oi1; }
            else v2 = fmaxf(v2, ov1);
            const size_t gi = (size_t)(batch * NTILES + bm) * N_ + n0 + tid;
            pval[gi] = v1; pidx[gi] = i1; pval2[gi] = v2;
        }
        if (!diag) {
            float v1 = cv1[tid][0]; int i1 = ci1[tid][0]; float v2 = cv2[tid][0];
            const float ov1 = cv1[tid][1]; const int oi1 = ci1[tid][1]; const float ov2 = cv2[tid][1];
            if (ov1 > v1 || (ov1 == v1 && oi1 < i1)) { v2 = fmaxf(v1, ov2); v1 = ov1; i1 = oi1; }
            else v2 = fmaxf(v2, ov1);
            const size_t gi = (size_t)(batch * NTILES + bn) * N_ + m0 + tid;
            pval[gi] = v1; pidx[gi] = i1; pval2[gi] = v2;
        }
    }
}

// -------------------------------------------------------------- combine ----
__global__ void combine_kernel(const float* __restrict__ pval, const int* __restrict__ pidx,
                               const float* __restrict__ pval2, int* __restrict__ fidx,
                               int* __restrict__ rcnt, int* __restrict__ ridx) {
    const int t = blockIdx.x * 256 + threadIdx.x;  // 16384
    const int batch = t >> 11, n = t & 2047;
    float v1 = -3.4e38f, v2 = -3.4e38f;
    int i1 = 0x7fffffff;
    for (int s = 0; s < NTILES; ++s) {
        const size_t gi = (size_t)(batch * NTILES + s) * N_ + n;
        const float ov1 = pval[gi]; const int oi1 = pidx[gi]; const float ov2 = pval2[gi];
        if (ov1 > v1 || (ov1 == v1 && oi1 < i1)) { v2 = fmaxf(v1, ov2); v1 = ov1; i1 = oi1; }
        else v2 = fmaxf(v2, ov1);
    }
    fidx[t] = i1;
    if (v1 - v2 < 1e-4f) {
        const int slot = atomicAdd(rcnt, 1);
        ridx[slot] = t;
    }
}

// --------------------------------------------------------------- rescue ----
// Exact fp32 re-argmax for near-tie rows, reading original x (coalesced over m).
__global__ __launch_bounds__(256) void rescue_kernel(const float* __restrict__ x,
                                                     const float* __restrict__ normpart,
                                                     const int* __restrict__ rcnt,
                                                     const int* __restrict__ ridx,
                                                     int* __restrict__ fidx) {
    const int cnt = *rcnt;
    const int tid = threadIdx.x;
    __shared__ float bv[256];
    __shared__ int bi[256];
    for (int rr = blockIdx.x; rr < cnt; rr += gridDim.x) {
        const int t = ridx[rr];
        const int batch = t >> 11, n = t & 2047;
        const float* xb = x + (size_t)batch * CN_;
        float s[8];
#pragma unroll
        for (int k = 0; k < 8; ++k) s[k] = 0.f;
        for (int c = 0; c < C_; ++c) {
            const float xc = xb[(size_t)c * N_ + n];
            const float* xr = xb + (size_t)c * N_;
#pragma unroll
            for (int k = 0; k < 8; ++k) s[k] += xc * xr[tid + (k << 8)];
        }
        float best = -3.4e38f;
        int besti = 0x7fffffff;
#pragma unroll
        for (int k = 0; k < 8; ++k) {
            const int m = tid + (k << 8);
            const float v = s[k] * rnorm_at(normpart, batch * N_ + m);
            if (m != n && v > best) { best = v; besti = m; }
        }
        bv[tid] = best; bi[tid] = besti;
        __syncthreads();
        for (int sft = 128; sft > 0; sft >>= 1) {
            if (tid < sft) {
                const float ov = bv[tid + sft]; const int oi = bi[tid + sft];
                if (ov > bv[tid] || (ov == bv[tid] && oi < bi[tid])) { bv[tid] = ov; bi[tid] = oi; }
            }
            __syncthreads();
        }
        if (tid == 0) fidx[t] = bi[0];
        __syncthreads();
    }
}

// ------------------------------- finish: gate softmax + gather + outputs ---
__global__ __launch_bounds__(256) void finish_kernel(const float* __restrict__ x,
                                                     const __hip_bfloat16* __restrict__ hiT,
                                                     const __hip_bfloat16* __restrict__ loT,
                                                     const float* __restrict__ W,
                                                     const int* __restrict__ fidx,
                                                     float* __restrict__ out) {
    const int batch = blockIdx.x & 7;
    const int nt = blockIdx.x >> 3;  // 0..127
    const int n0 = nt << 4;
    const int t = threadIdx.x;
    const int i = t & 15, cg = t >> 4;

    __shared__ float Wl[1024];
    __shared__ int il[16];
    __shared__ float l0r[16][17], l1r[16][17];
    __shared__ float w0s[16], w1s[16];

    for (int u = t; u < 1024; u += 256) Wl[u] = W[u];
    if (t < 16) il[t] = fidx[batch * N_ + n0 + t];
    __syncthreads();

    const float* xb = x + (size_t)batch * CN_ + n0 + i;
    const int myidx = il[i];
    const size_t row = ((size_t)batch * N_ + myidx) * C_ + cg * 16;

    float fvv[16];
    {
        const bf16x8* hp = (const bf16x8*)(hiT + row);
        const bf16x8* lp = (const bf16x8*)(loT + row);
#pragma unroll
        for (int v8 = 0; v8 < 2; ++v8) {
            const bf16x8 h = hp[v8];
            const bf16x8 g = lp[v8];
#pragma unroll
            for (int e = 0; e < 8; ++e) fvv[v8 * 8 + e] = b2f(h[e]) + b2f(g[e]);
        }
    }

    float l0 = 0.f, l1 = 0.f;
#pragma unroll
    for (int cc = 0; cc < 16; ++cc) {
        const int c = cg * 16 + cc;
        const float xv = xb[(size_t)c * N_];
        l0 += xv * Wl[c] + fvv[cc] * Wl[256 + c];
        l1 += xv * Wl[512 + c] + fvv[cc] * Wl[768 + c];
    }
    l0r[cg][i] = l0;
    l1r[cg][i] = l1;
    __syncthreads();
    if (t < 16) {
        float L0 = 0.f, L1 = 0.f;
#pragma unroll
        for (int g = 0; g < 16; ++g) { L0 += l0r[g][t]; L1 += l1r[g][t]; }
        const float mx = fmaxf(L0, L1);
        const float e0 = expf(L0 - mx);
        const float e1 = expf(L1 - mx);
        const float inv = 1.0f / (e0 + e1);
        w0s[t] = e0 * inv;
        w1s[t] = e1 * inv;
    }
    __syncthreads();
    const float w0 = w0s[i], w1 = w1s[i];

#pragma unroll
    for (int cc = 0; cc < 16; ++cc) {
        const int c = cg * 16 + cc;
        const size_t off = (size_t)batch * CN_ + (size_t)c * N_ + n0 + i;
        const float xv = xb[(size_t)c * N_];
        out[off] = xv * w0 + fvv[cc] * w1;
        out[TOT_ + off] = fvv[cc];
    }
}

// ---------------------------------------------------------------------------
extern "C" void kernel_launch(void* const* d_in, const int* in_sizes, int n_in,
                              void* d_out, int out_size, void* d_ws, size_t ws_size,
                              hipStream_t stream) {
    const float* x = (const float*)d_in[0];
    const float* W = (const float*)d_in[1];
    float* out = (float*)d_out;

    const size_t BF_BYTES = (size_t)TOT_ * 2;             // 8.39 MB each
    const size_t NORM_BYTES = (size_t)BN_ * 4;            // 64 KB
    const size_t P_BYTES = (size_t)B_ * NTILES * N_ * 4;  // 1 MB each

    uint8_t* p = (uint8_t*)d_ws;
    __hip_bfloat16* hiT = (__hip_bfloat16*)p; p += BF_BYTES;
    __hip_bfloat16* loT = (__hip_bfloat16*)p; p += BF_BYTES;
    float* normpart = (float*)p; p += 4 * NORM_BYTES;     // per-ctile partials
    float* pval = (float*)p; p += P_BYTES;
    int* pidx = (int*)p; p += P_BYTES;
    float* pval2 = (float*)p; p += P_BYTES;
    int* fidx = (int*)p; p += NORM_BYTES;
    int* rcnt = (int*)p; p += 256;
    int* ridx = (int*)p; p += NORM_BYTES;

    convert_kernel<<<1024, 256, 0, stream>>>(x, hiT, loT, normpart, rcnt);
    gram_mfma_kernel<<<B_ * NPAIRS, 256, 0, stream>>>(hiT, loT, normpart, pval, pidx, pval2);
    combine_kernel<<<64, 256, 0, stream>>>(pval, pidx, pval2, fidx, rcnt, ridx);
    rescue_kernel<<<64, 256, 0, stream>>>(x, normpart, rcnt, ridx, fidx);
    finish_kernel<<<1024, 256, 0, stream>>>(x, hiT, loT, W, fidx, out);
}